// Round 5
// baseline (594.916 us; speedup 1.0000x reference)
//
#include <hip/hip_runtime.h>
#include <hip/hip_bf16.h>
#include <hip/hip_fp16.h>
#include <math.h>

// GAT 3-layer forward, MI355X.
// CSR build (hierarchical scan) once; per layer one batch-fused register-tiled
// GEMM (X staged in LDS, W broadcast-read from L2; fp16 h output) and one
// batch-fused single-pass online-softmax aggregate (fp16 h gather, depth-2
// software pipeline). Interleaved layouts: h[(n*B+b)*M + c] (fp16),
// es[(n*B+b)*H + hd] (fp32).

#define NEG_SLOPE 0.2f

constexpr int NN   = 50000;   // nodes
constexpr int FIN  = 128;     // input features
constexpr int HC   = 64;      // H*C for layers 1,2
constexpr int NCLS = 16;      // layer-3 output

struct H16 { __half2 h[8]; };   // 16 fp16 = 32 B
struct H4  { __half2 h[2]; };   // 4 fp16 = 8 B

// ---------------- CSR build ----------------

__global__ void init_deg_kernel(int* deg, int N) {
    int t = blockIdx.x * blockDim.x + threadIdx.x;
    if (t < N) deg[t] = 1;  // self-loop
}

__global__ void hist_kernel(const int* __restrict__ ei, int* deg, int E) {
    int t = blockIdx.x * blockDim.x + threadIdx.x;
    if (t < E) atomicAdd(&deg[ei[E + t]], 1);   // dst = ei[E + t]
}

__global__ __launch_bounds__(1024) void scan1_kernel(
    const int* __restrict__ deg, int* __restrict__ rp,
    int* __restrict__ bsum, int N) {
    __shared__ int buf[1024];
    int i = blockIdx.x * 1024 + threadIdx.x;
    int v = (i < N) ? deg[i] : 0;
    buf[threadIdx.x] = v;
    __syncthreads();
#pragma unroll
    for (int off = 1; off < 1024; off <<= 1) {
        int t = (threadIdx.x >= (unsigned)off) ? buf[threadIdx.x - off] : 0;
        __syncthreads();
        buf[threadIdx.x] += t;
        __syncthreads();
    }
    if (i < N) rp[i] = buf[threadIdx.x] - v;       // exclusive, block-local
    if (threadIdx.x == 1023) bsum[blockIdx.x] = buf[1023];
}

__global__ void scan2_kernel(int* __restrict__ bsum, int nb,
                             int* __restrict__ rp, int N) {
    int lane = threadIdx.x;  // single wave; nb <= 64
    int v = (lane < nb) ? bsum[lane] : 0;
#pragma unroll
    for (int off = 1; off < 64; off <<= 1) {
        int t = __shfl_up(v, off);
        if (lane >= off) v += t;
    }
    if (lane < nb) bsum[lane] = v;   // inclusive
    if (lane == nb - 1) rp[N] = v;   // total
}

__global__ __launch_bounds__(1024) void scan3_kernel(
    int* __restrict__ rp, int* __restrict__ wp,
    const int* __restrict__ bsum, int N) {
    int i = blockIdx.x * 1024 + threadIdx.x;
    if (i >= N) return;
    int add = (blockIdx.x > 0) ? bsum[blockIdx.x - 1] : 0;
    int r = rp[i] + add;
    rp[i] = r;
    wp[i] = r;
}

__global__ void scatter_kernel(const int* __restrict__ ei, int* wp,
                               int* __restrict__ col, int E, int N) {
    int t = blockIdx.x * blockDim.x + threadIdx.x;
    int total = E + N;
    if (t >= total) return;
    if (t < E) {
        int s = ei[t];
        int d = ei[E + t];
        int pos = atomicAdd(&wp[d], 1);
        col[pos] = s;
    } else {
        int n = t - E;  // self-loop
        int pos = atomicAdd(&wp[n], 1);
        col[pos] = n;
    }
}

// ---------------- register-tiled GEMM + edge-logit epilogue ----------------
// h = X @ W; block computes NT nodes x M cols; thread owns RN x 4 acc block.
// X tile staged in LDS via coalesced float4 loads (one barrier); W read from
// global per k-step (L2-hot, ng-broadcast, 256B-coalesced). Hout in fp16.

template <int K, int M, int RN, int BF, bool IL>
__global__ __launch_bounds__(256) void gemm_kernel(
    const float* __restrict__ X, const float* __restrict__ W,
    const float* __restrict__ as_, const float* __restrict__ ad_,
    __half* __restrict__ Hout, float* __restrict__ Es, float* __restrict__ Ed,
    int N) {
    constexpr int G   = M / 4;       // col groups per node (16 or 4)
    constexpr int NG  = 256 / G;     // node groups per block
    constexpr int NT  = NG * RN;     // nodes per block
    constexpr int H   = M / 16;
    constexpr int LK  = K + 4;       // padded row (2-way LDS aliasing: free)
    __shared__ float xs[NT * LK];
    const int b = blockIdx.y;
    const int t = threadIdx.x;
    const int node00 = blockIdx.x * NT;

    // stage X tile: coalesced float4 loads, deep MLP, single barrier
    for (int idx = t * 4; idx < NT * K; idx += 1024) {
        int row = idx / K;
        int k   = idx & (K - 1);
        int node = node00 + row;
        int nc = (node < N) ? node : N - 1;   // clamp; stores guarded below
        const float* src = X + (IL ? ((size_t)nc * BF + b) * (size_t)K
                                   : ((size_t)b * N + nc) * (size_t)K) + k;
        *reinterpret_cast<float4*>(&xs[row * LK + k]) =
            *reinterpret_cast<const float4*>(src);
    }
    __syncthreads();

    const int cg = t % G;
    const int ng = t / G;
    const int c0 = cg * 4;
    const int node0 = node00 + ng * RN;

    float acc[RN][4];
#pragma unroll
    for (int j = 0; j < RN; ++j)
#pragma unroll
        for (int cc = 0; cc < 4; ++cc) acc[j][cc] = 0.f;

#pragma unroll 2
    for (int k = 0; k < K; k += 4) {
        float4 w0 = *reinterpret_cast<const float4*>(&W[(k + 0) * M + c0]);
        float4 w1 = *reinterpret_cast<const float4*>(&W[(k + 1) * M + c0]);
        float4 w2 = *reinterpret_cast<const float4*>(&W[(k + 2) * M + c0]);
        float4 w3 = *reinterpret_cast<const float4*>(&W[(k + 3) * M + c0]);
#pragma unroll
        for (int j = 0; j < RN; ++j) {
            float4 xv = *reinterpret_cast<const float4*>(
                &xs[(ng * RN + j) * LK + k]);
            acc[j][0] = fmaf(xv.x, w0.x, acc[j][0]);
            acc[j][1] = fmaf(xv.x, w0.y, acc[j][1]);
            acc[j][2] = fmaf(xv.x, w0.z, acc[j][2]);
            acc[j][3] = fmaf(xv.x, w0.w, acc[j][3]);
            acc[j][0] = fmaf(xv.y, w1.x, acc[j][0]);
            acc[j][1] = fmaf(xv.y, w1.y, acc[j][1]);
            acc[j][2] = fmaf(xv.y, w1.z, acc[j][2]);
            acc[j][3] = fmaf(xv.y, w1.w, acc[j][3]);
            acc[j][0] = fmaf(xv.z, w2.x, acc[j][0]);
            acc[j][1] = fmaf(xv.z, w2.y, acc[j][1]);
            acc[j][2] = fmaf(xv.z, w2.z, acc[j][2]);
            acc[j][3] = fmaf(xv.z, w2.w, acc[j][3]);
            acc[j][0] = fmaf(xv.w, w3.x, acc[j][0]);
            acc[j][1] = fmaf(xv.w, w3.y, acc[j][1]);
            acc[j][2] = fmaf(xv.w, w3.z, acc[j][2]);
            acc[j][3] = fmaf(xv.w, w3.w, acc[j][3]);
        }
    }

    const int hd = c0 >> 4;
    const float4 av = *reinterpret_cast<const float4*>(&as_[c0]);
    const float4 dv = *reinterpret_cast<const float4*>(&ad_[c0]);
#pragma unroll
    for (int j = 0; j < RN; ++j) {
        int node = node0 + j;
        float ps = acc[j][0] * av.x + acc[j][1] * av.y +
                   acc[j][2] * av.z + acc[j][3] * av.w;
        float pd = acc[j][0] * dv.x + acc[j][1] * dv.y +
                   acc[j][2] * dv.z + acc[j][3] * dv.w;
        ps += __shfl_xor(ps, 1); ps += __shfl_xor(ps, 2);
        pd += __shfl_xor(pd, 1); pd += __shfl_xor(pd, 2);
        if (node < N) {
            H4 hv;
            hv.h[0] = __float22half2_rn(make_float2(acc[j][0], acc[j][1]));
            hv.h[1] = __float22half2_rn(make_float2(acc[j][2], acc[j][3]));
            *reinterpret_cast<H4*>(&Hout[((size_t)node * BF + b) * M + c0]) = hv;
            if ((cg & 3) == 0) {
                Es[((size_t)node * BF + b) * H + hd] = ps;
                Ed[((size_t)node * BF + b) * H + hd] = pd;
            }
        }
    }
}

// ---------------- single-pass online-softmax aggregate ----------------
// Thin threads: t -> (n, hd, b). Depth-2 software pipeline: issue edge i+1
// loads (col/Es/h16) before computing edge i's exp+fma.

template <int H, bool RELU, bool OUTB, int BF>
__global__ __launch_bounds__(256) void agg_kernel(
    const int* __restrict__ rp, const int* __restrict__ col,
    const __half* __restrict__ Hm, const float* __restrict__ Es,
    const float* __restrict__ Ed, const float* __restrict__ bias,
    float* __restrict__ Out, int N) {
    constexpr int C = 16;
    constexpr int M = H * C;
    int t = blockIdx.x * 256 + threadIdx.x;
    if (t >= N * H * BF) return;
    int u = t;
    const int b  = u % BF; u /= BF;
    const int hd = u % H;  u /= H;
    const int n  = u;

    const float ed = Ed[((size_t)n * BF + b) * H + hd];
    const int beg = rp[n], end = rp[n + 1];

    float m = -1e30f, dn = 0.f;
    float acc[C];
#pragma unroll
    for (int j = 0; j < C; ++j) acc[j] = 0.f;

    // prologue: load edge `beg` (degree >= 1 always: self-loop)
    int i = beg;
    int sA = col[i];
    float esA = Es[((size_t)sA * BF + b) * H + hd];
    H16 hA = *reinterpret_cast<const H16*>(Hm + ((size_t)sA * BF + b) * M + hd * C);

    while (true) {
        // issue next edge's loads before computing current
        int inext = i + 1;
        bool more = (inext < end);
        int sB = 0; float esB = 0.f; H16 hB;
        if (more) {
            sB = col[inext];
            esB = Es[((size_t)sB * BF + b) * H + hd];
            hB = *reinterpret_cast<const H16*>(Hm + ((size_t)sB * BF + b) * M + hd * C);
        }

        float e = esA + ed;
        e = (e >= 0.f) ? e : NEG_SLOPE * e;
        float2 f0 = __half22float2(hA.h[0]);
        float2 f1 = __half22float2(hA.h[1]);
        float2 f2 = __half22float2(hA.h[2]);
        float2 f3 = __half22float2(hA.h[3]);
        float2 f4 = __half22float2(hA.h[4]);
        float2 f5 = __half22float2(hA.h[5]);
        float2 f6 = __half22float2(hA.h[6]);
        float2 f7 = __half22float2(hA.h[7]);
        if (e > m) {
            float sc = __expf(m - e);   // first iter: exp(-huge)=0
            m = e;
            dn = fmaf(dn, sc, 1.0f);    // ex = exp(e-m) = 1 exactly
            acc[0]=fmaf(acc[0],sc,f0.x);   acc[1]=fmaf(acc[1],sc,f0.y);
            acc[2]=fmaf(acc[2],sc,f1.x);   acc[3]=fmaf(acc[3],sc,f1.y);
            acc[4]=fmaf(acc[4],sc,f2.x);   acc[5]=fmaf(acc[5],sc,f2.y);
            acc[6]=fmaf(acc[6],sc,f3.x);   acc[7]=fmaf(acc[7],sc,f3.y);
            acc[8]=fmaf(acc[8],sc,f4.x);   acc[9]=fmaf(acc[9],sc,f4.y);
            acc[10]=fmaf(acc[10],sc,f5.x); acc[11]=fmaf(acc[11],sc,f5.y);
            acc[12]=fmaf(acc[12],sc,f6.x); acc[13]=fmaf(acc[13],sc,f6.y);
            acc[14]=fmaf(acc[14],sc,f7.x); acc[15]=fmaf(acc[15],sc,f7.y);
        } else {
            float ex = __expf(e - m);
            dn += ex;
            acc[0]=fmaf(ex,f0.x,acc[0]);   acc[1]=fmaf(ex,f0.y,acc[1]);
            acc[2]=fmaf(ex,f1.x,acc[2]);   acc[3]=fmaf(ex,f1.y,acc[3]);
            acc[4]=fmaf(ex,f2.x,acc[4]);   acc[5]=fmaf(ex,f2.y,acc[5]);
            acc[6]=fmaf(ex,f3.x,acc[6]);   acc[7]=fmaf(ex,f3.y,acc[7]);
            acc[8]=fmaf(ex,f4.x,acc[8]);   acc[9]=fmaf(ex,f4.y,acc[9]);
            acc[10]=fmaf(ex,f5.x,acc[10]); acc[11]=fmaf(ex,f5.y,acc[11]);
            acc[12]=fmaf(ex,f6.x,acc[12]); acc[13]=fmaf(ex,f6.y,acc[13]);
            acc[14]=fmaf(ex,f7.x,acc[14]); acc[15]=fmaf(ex,f7.y,acc[15]);
        }
        if (!more) break;
        i = inext; sA = sB; esA = esB; hA = hB;
    }

    float inv = 1.f / (dn + 1e-16f);
    const float* bp = bias + hd * C;
    float* op = OUTB ? (Out + ((size_t)b * N + n) * M + hd * C)
                     : (Out + ((size_t)n * BF + b) * M + hd * C);
    float vb[C];
#pragma unroll
    for (int j = 0; j < C; ++j) {
        float v = fmaf(acc[j], inv, bp[j]);
        if (RELU) v = fmaxf(v, 0.f);
        vb[j] = v;
    }
    *reinterpret_cast<float4*>(op + 0)  = make_float4(vb[0], vb[1], vb[2], vb[3]);
    *reinterpret_cast<float4*>(op + 4)  = make_float4(vb[4], vb[5], vb[6], vb[7]);
    *reinterpret_cast<float4*>(op + 8)  = make_float4(vb[8], vb[9], vb[10], vb[11]);
    *reinterpret_cast<float4*>(op + 12) = make_float4(vb[12], vb[13], vb[14], vb[15]);
}

// ---------------- launch ----------------

extern "C" void kernel_launch(void* const* d_in, const int* in_sizes, int n_in,
                              void* d_out, int out_size, void* d_ws, size_t ws_size,
                              hipStream_t stream) {
    const float* x   = (const float*)d_in[0];
    const int*   ei  = (const int*)d_in[1];
    const float* W1  = (const float*)d_in[2];
    const float* a1s = (const float*)d_in[3];
    const float* a1d = (const float*)d_in[4];
    const float* b1  = (const float*)d_in[5];
    const float* W2  = (const float*)d_in[6];
    const float* a2s = (const float*)d_in[7];
    const float* a2d = (const float*)d_in[8];
    const float* b2  = (const float*)d_in[9];
    const float* W3  = (const float*)d_in[10];
    const float* a3s = (const float*)d_in[11];
    const float* a3d = (const float*)d_in[12];
    const float* b3  = (const float*)d_in[13];
    float* outp = (float*)d_out;

    const int N  = NN;
    const int E  = in_sizes[1] / 2;
    const int ET = E + N;
    const int B  = in_sizes[0] / (N * FIN);
    const int NB1024 = (N + 1023) / 1024;

    char* ws = (char*)d_ws;
    size_t off = 0;
    auto alloc = [&](size_t bytes) -> void* {
        void* p = ws + off;
        off += (bytes + 255) & ~(size_t)255;
        return p;
    };
    int* deg  = (int*)alloc((size_t)N * 4);
    int* rp   = (int*)alloc((size_t)(N + 1) * 4);
    int* wp   = (int*)alloc((size_t)N * 4);
    int* bsum = (int*)alloc(64 * 4);
    int* col  = (int*)alloc((size_t)ET * 4);

    size_t fused_need = off + ((size_t)N * B * HC * 2 + 256)      // h fp16
                            + ((size_t)N * B * HC * 4 + 256)      // z fp32
                            + 2 * ((size_t)N * B * 4 * 4 + 256);  // es/ed
    bool fused = (B == 4) && (ws_size >= fused_need);
    int BF = fused ? 4 : 1;

    __half* h  = (__half*)alloc((size_t)N * BF * HC * 2);
    float* z   = (float*)alloc((size_t)N * BF * HC * 4);
    float* es  = (float*)alloc((size_t)N * BF * 4 * 4);
    float* edv = (float*)alloc((size_t)N * BF * 4 * 4);

    // CSR build (graph shared by all batches/layers)
    init_deg_kernel<<<(N + 255) / 256, 256, 0, stream>>>(deg, N);
    hist_kernel<<<(E + 255) / 256, 256, 0, stream>>>(ei, deg, E);
    scan1_kernel<<<NB1024, 1024, 0, stream>>>(deg, rp, bsum, N);
    scan2_kernel<<<1, 64, 0, stream>>>(bsum, NB1024, rp, N);
    scan3_kernel<<<NB1024, 1024, 0, stream>>>(rp, wp, bsum, N);
    scatter_kernel<<<(ET + 255) / 256, 256, 0, stream>>>(ei, wp, col, E, N);

    if (fused) {
        dim3 g12((N + 63) / 64, 4);     // NT=64
        dim3 g3((N + 63) / 64, 4);      // NT=64 (RN=1, G=4)
        int agg12 = (N * 4 * 4 + 255) / 256;
        int agg3  = (N * 4 + 255) / 256;
        gemm_kernel<128, 64, 4, 4, false><<<g12, 256, 0, stream>>>(x, W1, a1s, a1d, h, es, edv, N);
        agg_kernel<4, true, false, 4><<<agg12, 256, 0, stream>>>(rp, col, h, es, edv, b1, z, N);
        gemm_kernel<64, 64, 4, 4, true><<<g12, 256, 0, stream>>>(z, W2, a2s, a2d, h, es, edv, N);
        agg_kernel<4, true, false, 4><<<agg12, 256, 0, stream>>>(rp, col, h, es, edv, b2, z, N);
        gemm_kernel<64, 16, 1, 4, true><<<g3, 256, 0, stream>>>(z, W3, a3s, a3d, h, es, edv, N);
        agg_kernel<1, false, true, 4><<<agg3, 256, 0, stream>>>(rp, col, h, es, edv, b3, outp, N);
    } else {
        dim3 g12((N + 63) / 64, 1);
        dim3 g3((N + 63) / 64, 1);
        int agg12 = (N * 4 + 255) / 256;
        int agg3  = (N + 255) / 256;
        for (int b = 0; b < B; ++b) {
            const float* xb = x + (size_t)b * N * FIN;
            float* outb = outp + (size_t)b * N * NCLS;
            gemm_kernel<128, 64, 4, 1, false><<<g12, 256, 0, stream>>>(xb, W1, a1s, a1d, h, es, edv, N);
            agg_kernel<4, true, false, 1><<<agg12, 256, 0, stream>>>(rp, col, h, es, edv, b1, z, N);
            gemm_kernel<64, 64, 4, 1, false><<<g12, 256, 0, stream>>>(z, W2, a2s, a2d, h, es, edv, N);
            agg_kernel<4, true, false, 1><<<agg12, 256, 0, stream>>>(rp, col, h, es, edv, b2, z, N);
            gemm_kernel<64, 16, 1, 1, false><<<g3, 256, 0, stream>>>(z, W3, a3s, a3d, h, es, edv, N);
            agg_kernel<1, false, false, 1><<<agg3, 256, 0, stream>>>(rp, col, h, es, edv, b3, outb, N);
        }
    }
}

// Round 6
// 542.146 us; speedup vs baseline: 1.0973x; 1.0973x over previous
//
#include <hip/hip_runtime.h>
#include <hip/hip_bf16.h>
#include <hip/hip_fp16.h>
#include <math.h>

// GAT 3-layer forward, MI355X.
// CSR build once; per layer one batch-fused MFMA GEMM (fp16 operands in LDS,
// fp32 accum, edge-logit epilogue) and one batch-fused single-pass
// online-softmax aggregate (fp16 h gather, depth-2 pipeline).
// Interleaved layouts: h/z[(n*B+b)*M + c] (fp16), es[(n*B+b)*H + hd] (fp32).

#define NEG_SLOPE 0.2f

constexpr int NN   = 50000;
constexpr int FIN  = 128;
constexpr int HC   = 64;
constexpr int NCLS = 16;

typedef _Float16 half4 __attribute__((ext_vector_type(4)));
typedef float    f32x4 __attribute__((ext_vector_type(4)));

struct H16 { __half2 h[8]; };   // 16 fp16 = 32 B

// ---------------- CSR build ----------------

__global__ void init_deg_kernel(int* deg, int N) {
    int t = blockIdx.x * blockDim.x + threadIdx.x;
    if (t < N) deg[t] = 1;  // self-loop
}

__global__ void hist_kernel(const int* __restrict__ ei, int* deg, int E) {
    int t = blockIdx.x * blockDim.x + threadIdx.x;
    if (t < E) atomicAdd(&deg[ei[E + t]], 1);   // dst = ei[E + t]
}

__global__ __launch_bounds__(1024) void scan1_kernel(
    const int* __restrict__ deg, int* __restrict__ rp,
    int* __restrict__ bsum, int N) {
    __shared__ int buf[1024];
    int i = blockIdx.x * 1024 + threadIdx.x;
    int v = (i < N) ? deg[i] : 0;
    buf[threadIdx.x] = v;
    __syncthreads();
#pragma unroll
    for (int off = 1; off < 1024; off <<= 1) {
        int t = (threadIdx.x >= (unsigned)off) ? buf[threadIdx.x - off] : 0;
        __syncthreads();
        buf[threadIdx.x] += t;
        __syncthreads();
    }
    if (i < N) rp[i] = buf[threadIdx.x] - v;       // exclusive, block-local
    if (threadIdx.x == 1023) bsum[blockIdx.x] = buf[1023];
}

__global__ void scan2_kernel(int* __restrict__ bsum, int nb,
                             int* __restrict__ rp, int N) {
    int lane = threadIdx.x;  // single wave; nb <= 64
    int v = (lane < nb) ? bsum[lane] : 0;
#pragma unroll
    for (int off = 1; off < 64; off <<= 1) {
        int t = __shfl_up(v, off);
        if (lane >= off) v += t;
    }
    if (lane < nb) bsum[lane] = v;   // inclusive
    if (lane == nb - 1) rp[N] = v;   // total
}

__global__ __launch_bounds__(1024) void scan3_kernel(
    int* __restrict__ rp, int* __restrict__ wp,
    const int* __restrict__ bsum, int N) {
    int i = blockIdx.x * 1024 + threadIdx.x;
    if (i >= N) return;
    int add = (blockIdx.x > 0) ? bsum[blockIdx.x - 1] : 0;
    int r = rp[i] + add;
    rp[i] = r;
    wp[i] = r;
}

__global__ void scatter_kernel(const int* __restrict__ ei, int* wp,
                               int* __restrict__ col, int E, int N) {
    int t = blockIdx.x * blockDim.x + threadIdx.x;
    int total = E + N;
    if (t >= total) return;
    if (t < E) {
        int s = ei[t];
        int d = ei[E + t];
        int pos = atomicAdd(&wp[d], 1);
        col[pos] = s;
    } else {
        int n = t - E;  // self-loop
        int pos = atomicAdd(&wp[n], 1);
        col[pos] = n;
    }
}

// ---------------- W prep: fp32 [K][M] -> fp16 transposed [M][K] ----------------

__global__ void prep_w_kernel(const float* __restrict__ W1,
                              const float* __restrict__ W2,
                              const float* __restrict__ W3,
                              __half* __restrict__ Wt1,
                              __half* __restrict__ Wt2,
                              __half* __restrict__ Wt3) {
    int t = blockIdx.x * 256 + threadIdx.x;
    if (t < 64 * 128) { int c = t >> 7, k = t & 127; Wt1[t] = __float2half(W1[k * 64 + c]); }
    if (t < 64 * 64)  { int c = t >> 6, k = t & 63;  Wt2[t] = __float2half(W2[k * 64 + c]); }
    if (t < 16 * 64)  { int c = t >> 6, k = t & 63;  Wt3[t] = __float2half(W3[k * 16 + c]); }
}

// ---------------- MFMA GEMM + edge-logit epilogue ----------------
// h = X @ W, fp16 inputs / fp32 accum via v_mfma_f32_16x16x16_f16.
// Block = 256 thr = 4 waves; tile = 64 nodes x M cols; wave = 16 nodes.
// Layouts (classic 16x16x16): A[row=l%16][k=4*(l/16)+j], B[k][col=l%16],
// D[row=4*(l/16)+r][col=l%16]. X and W^T staged in LDS, rows padded +8 halves
// (2-way bank aliasing only). Epilogue: es/ed via 16-lane shfl reduction.

template <int K, int M, int BF, bool IN16>
__global__ __launch_bounds__(256) void gemm_mfma_kernel(
    const void* __restrict__ Xin, const __half* __restrict__ Wt_g,
    const float* __restrict__ as_, const float* __restrict__ ad_,
    __half* __restrict__ Hout, float* __restrict__ Es, float* __restrict__ Ed,
    int N) {
    constexpr int CT = M / 16;       // col tiles = heads
    constexpr int PK = K + 8;        // padded LDS row (halves)
    constexpr int KS = K / 16;       // mfma k-steps
    __shared__ _Float16 Xs[64 * PK];
    __shared__ _Float16 Ws[M * PK];
    const int b = blockIdx.y;
    const int t = threadIdx.x;
    const int node00 = blockIdx.x * 64;

    // stage W^T (fp16 [c][K] in global, prepped)
    {
        const float4* wsrc = reinterpret_cast<const float4*>(Wt_g);
        constexpr int WC8 = K / 8;
        for (int idx = t; idx < M * WC8; idx += 256) {
            int c = idx / WC8, kk = idx - c * WC8;
            *reinterpret_cast<float4*>(&Ws[c * PK + kk * 8]) = wsrc[idx];
        }
    }
    // stage X tile (fp32 -> cvt fp16, or fp16 copy), coalesced
    if (IN16) {
        const __half* Xh = (const __half*)Xin;
        constexpr int C8 = K / 8;
        for (int idx = t; idx < 64 * C8; idx += 256) {
            int row = idx / C8, k8 = idx - row * C8;
            int node = node00 + row;
            if (node >= N) node = N - 1;
            const float4* src = reinterpret_cast<const float4*>(
                Xh + ((size_t)node * BF + b) * K + k8 * 8);
            *reinterpret_cast<float4*>(&Xs[row * PK + k8 * 8]) = *src;
        }
    } else {
        const float* Xf = (const float*)Xin;
        constexpr int C4 = K / 4;
        for (int idx = t; idx < 64 * C4; idx += 256) {
            int row = idx / C4, k4 = idx - row * C4;
            int node = node00 + row;
            if (node >= N) node = N - 1;
            float4 xv = *reinterpret_cast<const float4*>(
                Xf + ((size_t)b * N + node) * K + k4 * 4);
            half4 hv;
            hv[0] = (_Float16)xv.x; hv[1] = (_Float16)xv.y;
            hv[2] = (_Float16)xv.z; hv[3] = (_Float16)xv.w;
            *reinterpret_cast<half4*>(&Xs[row * PK + k4 * 4]) = hv;
        }
    }
    __syncthreads();

    const int lane = t & 63;
    const int w    = t >> 6;
    const int l15  = lane & 15;
    const int lg   = lane >> 4;
    const int rowb = w * 16;

    f32x4 acc[CT];
#pragma unroll
    for (int ct = 0; ct < CT; ++ct)
#pragma unroll
        for (int r = 0; r < 4; ++r) acc[ct][r] = 0.f;

#pragma unroll
    for (int ks = 0; ks < KS; ++ks) {
        half4 a = *reinterpret_cast<const half4*>(
            &Xs[(rowb + l15) * PK + ks * 16 + lg * 4]);
#pragma unroll
        for (int ct = 0; ct < CT; ++ct) {
            half4 bf = *reinterpret_cast<const half4*>(
                &Ws[(ct * 16 + l15) * PK + ks * 16 + lg * 4]);
            acc[ct] = __builtin_amdgcn_mfma_f32_16x16x16f16(a, bf, acc[ct], 0, 0, 0);
        }
    }

    _Float16* Hh = reinterpret_cast<_Float16*>(Hout);
#pragma unroll
    for (int ct = 0; ct < CT; ++ct) {
        float a_s = as_[ct * 16 + l15];
        float a_d = ad_[ct * 16 + l15];
#pragma unroll
        for (int r = 0; r < 4; ++r) {
            int node = node00 + rowb + lg * 4 + r;
            float hv = acc[ct][r];
            float ps = hv * a_s, pd = hv * a_d;
            ps += __shfl_xor(ps, 1); ps += __shfl_xor(ps, 2);
            ps += __shfl_xor(ps, 4); ps += __shfl_xor(ps, 8);
            pd += __shfl_xor(pd, 1); pd += __shfl_xor(pd, 2);
            pd += __shfl_xor(pd, 4); pd += __shfl_xor(pd, 8);
            if (node < N) {
                Hh[((size_t)node * BF + b) * M + ct * 16 + l15] = (_Float16)hv;
                if (l15 == 0) {
                    Es[((size_t)node * BF + b) * CT + ct] = ps;
                    Ed[((size_t)node * BF + b) * CT + ct] = pd;
                }
            }
        }
    }
}

// ---------------- single-pass online-softmax aggregate ----------------
// Thin threads: t -> (n, hd, b). Depth-2 software pipeline. OUTH: write fp16
// interleaved (feeds next MFMA gemm); else fp32 (final output).

template <int H, bool RELU, bool OUTB, bool OUTH, int BF>
__global__ __launch_bounds__(256) void agg_kernel(
    const int* __restrict__ rp, const int* __restrict__ col,
    const __half* __restrict__ Hm, const float* __restrict__ Es,
    const float* __restrict__ Ed, const float* __restrict__ bias,
    void* __restrict__ Out, int N) {
    constexpr int C = 16;
    constexpr int M = H * C;
    int t = blockIdx.x * 256 + threadIdx.x;
    if (t >= N * H * BF) return;
    int u = t;
    const int b  = u % BF; u /= BF;
    const int hd = u % H;  u /= H;
    const int n  = u;

    const float ed = Ed[((size_t)n * BF + b) * H + hd];
    const int beg = rp[n], end = rp[n + 1];

    float m = -1e30f, dn = 0.f;
    float acc[C];
#pragma unroll
    for (int j = 0; j < C; ++j) acc[j] = 0.f;

    // prologue: load edge `beg` (degree >= 1 always: self-loop)
    int i = beg;
    int sA = col[i];
    float esA = Es[((size_t)sA * BF + b) * H + hd];
    H16 hA = *reinterpret_cast<const H16*>(Hm + ((size_t)sA * BF + b) * M + hd * C);

    while (true) {
        int inext = i + 1;
        bool more = (inext < end);
        int sB = 0; float esB = 0.f; H16 hB;
        if (more) {
            sB = col[inext];
            esB = Es[((size_t)sB * BF + b) * H + hd];
            hB = *reinterpret_cast<const H16*>(Hm + ((size_t)sB * BF + b) * M + hd * C);
        }

        float e = esA + ed;
        e = (e >= 0.f) ? e : NEG_SLOPE * e;
        float2 f0 = __half22float2(hA.h[0]);
        float2 f1 = __half22float2(hA.h[1]);
        float2 f2 = __half22float2(hA.h[2]);
        float2 f3 = __half22float2(hA.h[3]);
        float2 f4 = __half22float2(hA.h[4]);
        float2 f5 = __half22float2(hA.h[5]);
        float2 f6 = __half22float2(hA.h[6]);
        float2 f7 = __half22float2(hA.h[7]);
        if (e > m) {
            float sc = __expf(m - e);   // first iter: exp(-huge)=0
            m = e;
            dn = fmaf(dn, sc, 1.0f);    // ex = exp(e-m) = 1 exactly
            acc[0]=fmaf(acc[0],sc,f0.x);   acc[1]=fmaf(acc[1],sc,f0.y);
            acc[2]=fmaf(acc[2],sc,f1.x);   acc[3]=fmaf(acc[3],sc,f1.y);
            acc[4]=fmaf(acc[4],sc,f2.x);   acc[5]=fmaf(acc[5],sc,f2.y);
            acc[6]=fmaf(acc[6],sc,f3.x);   acc[7]=fmaf(acc[7],sc,f3.y);
            acc[8]=fmaf(acc[8],sc,f4.x);   acc[9]=fmaf(acc[9],sc,f4.y);
            acc[10]=fmaf(acc[10],sc,f5.x); acc[11]=fmaf(acc[11],sc,f5.y);
            acc[12]=fmaf(acc[12],sc,f6.x); acc[13]=fmaf(acc[13],sc,f6.y);
            acc[14]=fmaf(acc[14],sc,f7.x); acc[15]=fmaf(acc[15],sc,f7.y);
        } else {
            float ex = __expf(e - m);
            dn += ex;
            acc[0]=fmaf(ex,f0.x,acc[0]);   acc[1]=fmaf(ex,f0.y,acc[1]);
            acc[2]=fmaf(ex,f1.x,acc[2]);   acc[3]=fmaf(ex,f1.y,acc[3]);
            acc[4]=fmaf(ex,f2.x,acc[4]);   acc[5]=fmaf(ex,f2.y,acc[5]);
            acc[6]=fmaf(ex,f3.x,acc[6]);   acc[7]=fmaf(ex,f3.y,acc[7]);
            acc[8]=fmaf(ex,f4.x,acc[8]);   acc[9]=fmaf(ex,f4.y,acc[9]);
            acc[10]=fmaf(ex,f5.x,acc[10]); acc[11]=fmaf(ex,f5.y,acc[11]);
            acc[12]=fmaf(ex,f6.x,acc[12]); acc[13]=fmaf(ex,f6.y,acc[13]);
            acc[14]=fmaf(ex,f7.x,acc[14]); acc[15]=fmaf(ex,f7.y,acc[15]);
        }
        if (!more) break;
        i = inext; sA = sB; esA = esB; hA = hB;
    }

    float inv = 1.f / (dn + 1e-16f);
    const float* bp = bias + hd * C;
    float vb[C];
#pragma unroll
    for (int j = 0; j < C; ++j) {
        float v = fmaf(acc[j], inv, bp[j]);
        if (RELU) v = fmaxf(v, 0.f);
        vb[j] = v;
    }
    if (OUTH) {
        __half* op = (__half*)Out + ((size_t)n * BF + b) * M + hd * C;
        H16 hv;
#pragma unroll
        for (int j = 0; j < 8; ++j)
            hv.h[j] = __float22half2_rn(make_float2(vb[2 * j], vb[2 * j + 1]));
        *reinterpret_cast<H16*>(op) = hv;
    } else {
        float* op = OUTB ? ((float*)Out + ((size_t)b * N + n) * M + hd * C)
                         : ((float*)Out + ((size_t)n * BF + b) * M + hd * C);
        *reinterpret_cast<float4*>(op + 0)  = make_float4(vb[0], vb[1], vb[2], vb[3]);
        *reinterpret_cast<float4*>(op + 4)  = make_float4(vb[4], vb[5], vb[6], vb[7]);
        *reinterpret_cast<float4*>(op + 8)  = make_float4(vb[8], vb[9], vb[10], vb[11]);
        *reinterpret_cast<float4*>(op + 12) = make_float4(vb[12], vb[13], vb[14], vb[15]);
    }
}

// ---------------- launch ----------------

extern "C" void kernel_launch(void* const* d_in, const int* in_sizes, int n_in,
                              void* d_out, int out_size, void* d_ws, size_t ws_size,
                              hipStream_t stream) {
    const float* x   = (const float*)d_in[0];
    const int*   ei  = (const int*)d_in[1];
    const float* W1  = (const float*)d_in[2];
    const float* a1s = (const float*)d_in[3];
    const float* a1d = (const float*)d_in[4];
    const float* b1  = (const float*)d_in[5];
    const float* W2  = (const float*)d_in[6];
    const float* a2s = (const float*)d_in[7];
    const float* a2d = (const float*)d_in[8];
    const float* b2  = (const float*)d_in[9];
    const float* W3  = (const float*)d_in[10];
    const float* a3s = (const float*)d_in[11];
    const float* a3d = (const float*)d_in[12];
    const float* b3  = (const float*)d_in[13];
    float* outp = (float*)d_out;

    const int N  = NN;
    const int E  = in_sizes[1] / 2;
    const int ET = E + N;
    const int B  = in_sizes[0] / (N * FIN);
    const int NB1024 = (N + 1023) / 1024;

    char* ws = (char*)d_ws;
    size_t off = 0;
    auto alloc = [&](size_t bytes) -> void* {
        void* p = ws + off;
        off += (bytes + 255) & ~(size_t)255;
        return p;
    };
    int* deg  = (int*)alloc((size_t)N * 4);
    int* rp   = (int*)alloc((size_t)(N + 1) * 4);
    int* wp   = (int*)alloc((size_t)N * 4);
    int* bsum = (int*)alloc(64 * 4);
    int* col  = (int*)alloc((size_t)ET * 4);
    __half* Wt1 = (__half*)alloc(64 * 128 * 2);
    __half* Wt2 = (__half*)alloc(64 * 64 * 2);
    __half* Wt3 = (__half*)alloc(16 * 64 * 2);

    size_t fused_need = off + 2 * ((size_t)N * B * HC * 2 + 256)      // h,z fp16
                            + 2 * ((size_t)N * B * 4 * 4 + 256);      // es/ed
    bool fused = (B == 4) && (ws_size >= fused_need);
    int BF = fused ? 4 : 1;

    __half* h  = (__half*)alloc((size_t)N * BF * HC * 2);
    __half* z  = (__half*)alloc((size_t)N * BF * HC * 2);
    float* es  = (float*)alloc((size_t)N * BF * 4 * 4);
    float* edv = (float*)alloc((size_t)N * BF * 4 * 4);

    // CSR build + W prep (shared by all batches/layers)
    init_deg_kernel<<<(N + 255) / 256, 256, 0, stream>>>(deg, N);
    hist_kernel<<<(E + 255) / 256, 256, 0, stream>>>(ei, deg, E);
    scan1_kernel<<<NB1024, 1024, 0, stream>>>(deg, rp, bsum, N);
    scan2_kernel<<<1, 64, 0, stream>>>(bsum, NB1024, rp, N);
    scan3_kernel<<<NB1024, 1024, 0, stream>>>(rp, wp, bsum, N);
    scatter_kernel<<<(ET + 255) / 256, 256, 0, stream>>>(ei, wp, col, E, N);
    prep_w_kernel<<<32, 256, 0, stream>>>(W1, W2, W3, Wt1, Wt2, Wt3);

    if (fused) {
        dim3 g((N + 63) / 64, 4);
        int agg12 = (N * 4 * 4 + 255) / 256;
        int agg3  = (N * 4 + 255) / 256;
        gemm_mfma_kernel<128, 64, 4, false><<<g, 256, 0, stream>>>(x, Wt1, a1s, a1d, h, es, edv, N);
        agg_kernel<4, true, false, true, 4><<<agg12, 256, 0, stream>>>(rp, col, h, es, edv, b1, z, N);
        gemm_mfma_kernel<64, 64, 4, true><<<g, 256, 0, stream>>>(z, Wt2, a2s, a2d, h, es, edv, N);
        agg_kernel<4, true, false, true, 4><<<agg12, 256, 0, stream>>>(rp, col, h, es, edv, b2, z, N);
        gemm_mfma_kernel<64, 16, 4, true><<<g, 256, 0, stream>>>(z, Wt3, a3s, a3d, h, es, edv, N);
        agg_kernel<1, false, true, false, 4><<<agg3, 256, 0, stream>>>(rp, col, h, es, edv, b3, outp, N);
    } else {
        dim3 g((N + 63) / 64, 1);
        int agg12 = (N * 4 + 255) / 256;
        int agg3  = (N + 255) / 256;
        for (int b = 0; b < B; ++b) {
            const float* xb = x + (size_t)b * N * FIN;
            float* outb = outp + (size_t)b * N * NCLS;
            gemm_mfma_kernel<128, 64, 1, false><<<g, 256, 0, stream>>>(xb, Wt1, a1s, a1d, h, es, edv, N);
            agg_kernel<4, true, false, true, 1><<<agg12, 256, 0, stream>>>(rp, col, h, es, edv, b1, z, N);
            gemm_mfma_kernel<64, 64, 1, true><<<g, 256, 0, stream>>>(z, Wt2, a2s, a2d, h, es, edv, N);
            agg_kernel<4, true, false, true, 1><<<agg12, 256, 0, stream>>>(rp, col, h, es, edv, b2, z, N);
            gemm_mfma_kernel<64, 16, 1, true><<<g, 256, 0, stream>>>(z, Wt3, a3s, a3d, h, es, edv, N);
            agg_kernel<1, false, false, false, 1><<<agg3, 256, 0, stream>>>(rp, col, h, es, edv, b3, outb, N);
        }
    }
}